// Round 16
// baseline (227.991 us; speedup 1.0000x reference)
//
#include <hip/hip_runtime.h>
#include <hip/hip_bf16.h>
#include <stdint.h>

// B=4, T=2048, INPUT_DIM=1024, DIM=64, H=16
typedef __attribute__((ext_vector_type(8))) short bf16x8;
typedef __attribute__((ext_vector_type(4))) short s16x4;
typedef __attribute__((ext_vector_type(4))) float f32x4;
typedef __attribute__((ext_vector_type(16))) float f32x16;

__device__ __forceinline__ void mfma_bf16(f32x4& c, bf16x8 a, bf16x8 b) {
  asm("v_mfma_f32_16x16x32_bf16 %0, %1, %2, %0" : "+v"(c) : "v"(a), "v"(b));
}
__device__ __forceinline__ void mfma32_bf16(f32x16& c, bf16x8 a, bf16x8 b) {
  asm("v_mfma_f32_32x32x16_bf16 %0, %1, %2, %0" : "+v"(c) : "v"(a), "v"(b));
}

__device__ __forceinline__ void gload_lds16(const void* g, void* lds) {
  __builtin_amdgcn_global_load_lds(
      (const __attribute__((address_space(1))) void*)g,
      (__attribute__((address_space(3))) void*)lds, 16, 0, 0);
}

// ---------------- fused prep: x cvt (blocks 0..2047), w_qkv T (2048..5119),
// ---------------- w_out T (5120..6143). Branch is block-uniform. ----------------
__global__ __launch_bounds__(256) void prep(
    const float* __restrict__ x, __hip_bfloat16* __restrict__ x_bf,
    const float* __restrict__ w_qkv, __hip_bfloat16* __restrict__ wqkv_t,
    const float* __restrict__ w_out, __hip_bfloat16* __restrict__ wout_t) {
  __shared__ float tile[32][33];
  const int bid = blockIdx.x, tid = threadIdx.x;
  if (bid < 2048) {
    int i = bid * 256 + tid;  // grid-stride x4 over 2M float4s
#pragma unroll
    for (int it = 0; it < 4; ++it) {
      float4 v = reinterpret_cast<const float4*>(x)[i];
      __hip_bfloat162 a = __float22bfloat162_rn(make_float2(v.x, v.y));
      __hip_bfloat162 b = __float22bfloat162_rn(make_float2(v.z, v.w));
      reinterpret_cast<__hip_bfloat162*>(x_bf)[i * 2] = a;
      reinterpret_cast<__hip_bfloat162*>(x_bf)[i * 2 + 1] = b;
      i += 2048 * 256;
    }
  } else {
    const float* in;
    __hip_bfloat16* outp;
    int R, C, bx, by;
    if (bid < 5120) {  // w_qkv: [1024][3072] -> [3072][1024]
      int idx = bid - 2048;
      in = w_qkv; outp = wqkv_t; R = 1024; C = 3072;
      bx = idx % 96; by = idx / 96;
    } else {           // w_out: [1024][1024] -> [1024][1024]^T
      int idx = bid - 5120;
      in = w_out; outp = wout_t; R = 1024; C = 1024;
      bx = idx & 31; by = idx >> 5;
    }
    const int tx = tid & 31, ty = tid >> 5;
    const int c0 = bx * 32, r0 = by * 32;
#pragma unroll
    for (int k = 0; k < 4; k++)
      tile[ty + 8 * k][tx] = in[(size_t)(r0 + ty + 8 * k) * C + c0 + tx];
    __syncthreads();
#pragma unroll
    for (int k = 0; k < 4; k++)
      outp[(size_t)(c0 + ty + 8 * k) * R + r0 + tx] =
          __float2bfloat16(tile[tx][ty + 8 * k]);
  }
}

// ---------------- bf16 GEMM, m97 structure: 128x128 tile, BK=32 ----------------
// 512 blocks (2/CU) — grid fills the machine for the N=1024 GEMMs.
// MODE 1: f32 out + bias ; MODE 2: V-tiles -> C^T scatter into Vt [bh][d][t]
template <int MODE>
__global__ __launch_bounds__(256) void gemm_bf16(
    const __hip_bfloat16* __restrict__ A, const __hip_bfloat16* __restrict__ Bt,
    int M, int N, int K,
    __hip_bfloat16* __restrict__ vt,
    float* __restrict__ outp, const float* __restrict__ bias) {
  constexpr int BK = 32;
  __shared__ __align__(16) __hip_bfloat16 As[128 * BK];
  __shared__ __align__(16) __hip_bfloat16 Bs[128 * BK];
  const int tid = threadIdx.x;
  const int wave = tid >> 6, lane = tid & 63;
  const int wr = wave >> 1, wc = wave & 1;
  const int m0 = blockIdx.y * 128;
  const int n0 = (MODE == 2 ? 2048 : 0) + blockIdx.x * 128;

  f32x4 acc[4][4];
#pragma unroll
  for (int i = 0; i < 4; i++)
#pragma unroll
    for (int j = 0; j < 4; j++) acc[i][j] = (f32x4)(0.0f);

  const int c0 = wave * 2, c1 = c0 + 1;
  const int srow0 = c0 * 16 + (lane >> 2);
  const int srow1 = c1 * 16 + (lane >> 2);
  const int scol = (lane & 3) * 8;
  const __hip_bfloat16* Ag0 = A + (size_t)(m0 + srow0) * K + scol;
  const __hip_bfloat16* Ag1 = A + (size_t)(m0 + srow1) * K + scol;
  const __hip_bfloat16* Bg0 = Bt + (size_t)(n0 + srow0) * K + scol;
  const __hip_bfloat16* Bg1 = Bt + (size_t)(n0 + srow1) * K + scol;
  __hip_bfloat16* AsP0 = &As[c0 * 512];
  __hip_bfloat16* AsP1 = &As[c1 * 512];
  __hip_bfloat16* BsP0 = &Bs[c0 * 512];
  __hip_bfloat16* BsP1 = &Bs[c1 * 512];

  for (int kk = 0; kk < K; kk += BK) {
    gload_lds16(Ag0 + kk, AsP0);
    gload_lds16(Ag1 + kk, AsP1);
    gload_lds16(Bg0 + kk, BsP0);
    gload_lds16(Bg1 + kk, BsP1);
    __syncthreads();
    bf16x8 af[4], bfr[4];
#pragma unroll
    for (int i = 0; i < 4; i++)
      af[i] = *(const bf16x8*)&As[(wr * 64 + i * 16 + (lane & 15)) * BK + (lane >> 4) * 8];
#pragma unroll
    for (int j = 0; j < 4; j++)
      bfr[j] = *(const bf16x8*)&Bs[(wc * 64 + j * 16 + (lane & 15)) * BK + (lane >> 4) * 8];
#pragma unroll
    for (int i = 0; i < 4; i++)
#pragma unroll
      for (int j = 0; j < 4; j++) {
        if constexpr (MODE == 2)
          mfma_bf16(acc[i][j], bfr[j], af[i]);  // D = C^T fragment
        else
          mfma_bf16(acc[i][j], af[i], bfr[j]);
      }
    __syncthreads();
  }

  if constexpr (MODE == 2) {
#pragma unroll
    for (int j = 0; j < 4; j++) {
#pragma unroll
      for (int r = 0; r < 4; r++) {
        int nrow = n0 + wc * 64 + j * 16 + (lane >> 4) * 4 + r;  // 2048 + h*64 + d
        int h = (nrow >> 6) & 15;
        int d = nrow & 63;
#pragma unroll
        for (int i = 0; i < 4; i++) {
          int tcol = m0 + wr * 64 + i * 16 + (lane & 15);  // b*2048 + t
          int b = tcol >> 11, t = tcol & 2047;
          vt[(((size_t)b * 16 + h) * 64 + d) * 2048 + t] = __float2bfloat16(acc[i][j][r]);
        }
      }
    }
  } else {
#pragma unroll
    for (int j = 0; j < 4; j++) {
      int col = n0 + wc * 64 + j * 16 + (lane & 15);
      float bv = bias[col];
#pragma unroll
      for (int i = 0; i < 4; i++) {
#pragma unroll
        for (int r = 0; r < 4; r++) {
          int row = m0 + wr * 64 + i * 16 + (lane >> 4) * 4 + r;
          outp[(size_t)row * N + col] = acc[i][j][r] + bv;
        }
      }
    }
  }
}

// ---------------- 256x256 4-phase GEMM for Q/K (T2+T3+T5), 256 blocks ----------------
__global__ __launch_bounds__(512, 2) void gemm256_qk(
    const __hip_bfloat16* __restrict__ A, const __hip_bfloat16* __restrict__ Bt,
    __hip_bfloat16* __restrict__ qb, __hip_bfloat16* __restrict__ kb) {
  __shared__ __align__(16) __hip_bfloat16 lds[65536];  // 128KB
  char* ldsB = (char*)lds;
  const int tid = threadIdx.x, wave = tid >> 6, lane = tid & 63;
  const int wr = wave >> 2, wc = wave & 3;
  const int r15 = lane & 15, hi = lane >> 4;
  const int m0 = blockIdx.y * 256, n0 = blockIdx.x * 256;

  f32x4 acc[8][4];
#pragma unroll
  for (int i = 0; i < 8; i++)
#pragma unroll
    for (int j = 0; j < 4; j++) acc[i][j] = (f32x4)(0.0f);

  const int srow = lane >> 3;
  const int q8 = (lane & 7) ^ srow;  // pre-swizzled source chunk (rule #21)

  const int cs0 = ((hi) ^ (r15 & 7)) << 4;
  const int cs1 = ((4 + hi) ^ (r15 & 7)) << 4;

#define G256_STAGE_HALF(kt, tb, h)                                                     \
  do {                                                                                 \
    const __hip_bfloat16* gsrc_ = ((h) < 2)                                            \
        ? A + (size_t)(m0 + (h) * 128) * 1024 + (kt) * 64                              \
        : Bt + (size_t)(n0 + ((h) - 2) * 128) * 1024 + (kt) * 64;                      \
    char* dst_ = ldsB + (tb) * 65536 + (h) * 16384 + wave * 2048;                      \
    gload_lds16(gsrc_ + (size_t)(wave * 16 + srow) * 1024 + q8 * 8, dst_);             \
    gload_lds16(gsrc_ + (size_t)(wave * 16 + 8 + srow) * 1024 + q8 * 8, dst_ + 1024);  \
  } while (0)

#pragma unroll
  for (int h = 0; h < 4; h++) G256_STAGE_HALF(0, 0, h);
  asm volatile("s_waitcnt vmcnt(0)" ::: "memory");
  __builtin_amdgcn_s_barrier();

  bf16x8 af[4][2];
  for (int kt = 0; kt < 16; ++kt) {
    const int cur = kt & 1;
    const char* ab_ = ldsB + cur * 65536 + wr * 16384;
    const char* bb_ = ldsB + cur * 65536 + 32768 + (wc >> 1) * 16384;
#pragma unroll
    for (int p = 0; p < 4; p++) {
      const int qm = p >> 1, qn = p & 1;
      if (qn == 0) {
#pragma unroll
        for (int m = 0; m < 4; m++) {
          int hrow = (qm * 4 + m) * 16 + r15;
          af[m][0] = *(const bf16x8*)(ab_ + hrow * 128 + cs0);
          af[m][1] = *(const bf16x8*)(ab_ + hrow * 128 + cs1);
        }
      }
      bf16x8 bfv[2][2];
#pragma unroll
      for (int n = 0; n < 2; n++) {
        int hrow = (wc & 1) * 64 + (qn * 2 + n) * 16 + r15;
        bfv[n][0] = *(const bf16x8*)(bb_ + hrow * 128 + cs0);
        bfv[n][1] = *(const bf16x8*)(bb_ + hrow * 128 + cs1);
      }
      if (kt < 15) G256_STAGE_HALF(kt + 1, cur ^ 1, p);
      __builtin_amdgcn_s_barrier();
      asm volatile("s_waitcnt lgkmcnt(0)" ::: "memory");
      __builtin_amdgcn_sched_barrier(0);
      __builtin_amdgcn_s_setprio(1);
#pragma unroll
      for (int m = 0; m < 4; m++)
#pragma unroll
        for (int n = 0; n < 2; n++)
#pragma unroll
          for (int ks = 0; ks < 2; ks++)
            mfma_bf16(acc[qm * 4 + m][qn * 2 + n], af[m][ks], bfv[n][ks]);
      __builtin_amdgcn_s_setprio(0);
      if (p == 3) asm volatile("s_waitcnt vmcnt(0)" ::: "memory");
      __builtin_amdgcn_s_barrier();
    }
  }
#undef G256_STAGE_HALF

#pragma unroll
  for (int j = 0; j < 4; j++) {
    int col = n0 + wc * 64 + j * 16 + r15;
    int sel = col >> 10;  // 0=Q, 1=K
    int h = (col >> 6) & 15;
    int d = col & 63;
    __hip_bfloat16* dst = sel ? kb : qb;
    float scl = sel ? 1.0f : 0.18033688f;  // Q: 1/sqrt(64) * log2(e)
#pragma unroll
    for (int i = 0; i < 8; i++) {
#pragma unroll
      for (int r = 0; r < 4; r++) {
        int row = m0 + wr * 128 + i * 16 + hi * 4 + r;
        int b = row >> 11, t = row & 2047;
        dst[(((size_t)b * 16 + h) * 2048 + t) * 64 + d] = __float2bfloat16(acc[i][j][r] * scl);
      }
    }
  }
}

// ---------------- flash attention, 8 waves, 32x32 MFMA, NO-MAX softmax ----------------
// ROUND-15 structure (runtime 3-buffer rotation, l-via-builtin-MFMA) with ONE
// delta: per-tile s0/s1 zero-init (32 v_mov/tile) replaced by a PERSISTENT zero
// vector zc used as the C operand of the first QK MFMA pair (builtin form, the
// r12-proven safe path). zc kept live via opaque asm so it isn't rematerialized.
__global__ __launch_bounds__(512, 4) void attn_fwd(
    const __hip_bfloat16* __restrict__ Qb, const __hip_bfloat16* __restrict__ Kb,
    const __hip_bfloat16* __restrict__ Vtg, __hip_bfloat16* __restrict__ Ob) {
  constexpr int T = 2048, NT = T / 64;
  __shared__ __align__(16) __hip_bfloat16 Ks[3][4096];  // [key][d] image, swizzled
  __shared__ __align__(16) __hip_bfloat16 Vs[3][4096];  // [d][key] image, swizzled
  const int tid = threadIdx.x, wave = tid >> 6, lane = tid & 63;

  // XCD-aware swizzle: 512 blocks = 8 XCD x 64; XCD x gets bh 8x..8x+7
  int id = ((int)blockIdx.x & 7) * 64 + ((int)blockIdx.x >> 3);
  const int bh = id >> 3, q0 = (id & 7) * 256;
  const size_t baseQ = (size_t)bh * T * 64;
  const size_t baseV = (size_t)bh * 64 * T;
  const int l31 = lane & 31, half = lane >> 5;

  // Q fragments (B-operand): lane holds Q[qrow=l31][k = 16ks + half*8 + j]
  bf16x8 qf[4];
  const int qrow = q0 + wave * 32 + l31;
#pragma unroll
  for (int ks = 0; ks < 4; ks++)
    qf[ks] = *(const bf16x8*)&Qb[baseQ + (size_t)qrow * 64 + ks * 16 + half * 8];

  f32x16 o0 = (f32x16)(0.0f), o1 = (f32x16)(0.0f);
  f32x16 l_acc = (f32x16)(0.0f);  // l via builtin MFMA (all regs = l[qrow])
  bf16x8 onesv;                   // bf16 1.0 splat (A-operand)
#pragma unroll
  for (int j = 0; j < 8; j++) onesv[j] = (short)0x3F80;
  f32x16 zc = (f32x16)(0.0f);     // persistent zero C-operand for QK first MFMA
  asm("" : "+v"(zc));             // opaque: keep in regs, no rematerialized movs
  f32x16 s0, s1;
  bf16x8 pA0, pA1, pB0, pB1;  // packed P fragments (keys 0-15,16-31,32-47,48-63)

  const int sr = lane >> 3;         // 0..7
  const int q8 = (lane & 7) ^ sr;   // pre-swizzled 16B-chunk within row
  const char* KgB = (const char*)(Kb + baseQ);
  const char* VgB = (const char*)(Vtg + baseV);
  const int swz = (l31 & 7) << 4;   // read-side XOR (row&7 = lane&7)

#define STAGE(kt, buf)                                                                            \
  do {                                                                                            \
    gload_lds16(KgB + (size_t)((kt) * 64 + wave * 8 + sr) * 128 + q8 * 16,                        \
                (char*)Ks[buf] + wave * 1024);                                                    \
    gload_lds16(VgB + (size_t)(wave * 8 + sr) * 4096 + (kt) * 128 + q8 * 16,                      \
                (char*)Vs[buf] + wave * 1024);                                                    \
  } while (0)

#define QK_TILE(buf)                                                                              \
  do {                                                                                            \
    const char* KsB_ = (const char*)Ks[buf];                                                      \
    __builtin_amdgcn_s_setprio(1);                                                                \
    {                                                                                             \
      bf16x8 kf0 = *(const bf16x8*)(KsB_ + ((l31 * 128 + 0 * 32 + half * 16) ^ swz));             \
      bf16x8 kf1 = *(const bf16x8*)(KsB_ + (((32 + l31) * 128 + 0 * 32 + half * 16) ^ swz));      \
      s0 = __builtin_amdgcn_mfma_f32_32x32x16_bf16(kf0, qf[0], zc, 0, 0, 0);                      \
      s1 = __builtin_amdgcn_mfma_f32_32x32x16_bf16(kf1, qf[0], zc, 0, 0, 0);                      \
    }                                                                                             \
    _Pragma("unroll") for (int ks = 1; ks < 4; ks++) {                                            \
      bf16x8 kf0 = *(const bf16x8*)(KsB_ + ((l31 * 128 + ks * 32 + half * 16) ^ swz));            \
      bf16x8 kf1 = *(const bf16x8*)(KsB_ + (((32 + l31) * 128 + ks * 32 + half * 16) ^ swz));     \
      mfma32_bf16(s0, kf0, qf[ks]);                                                               \
      mfma32_bf16(s1, kf1, qf[ks]);                                                               \
    }                                                                                             \
    __builtin_amdgcn_s_setprio(0);                                                                \
  } while (0)

  // no-max softmax: P = 2^s; pack into pA/pB; s0/s1 die (l computed in PV via MFMA)
#define SMAX_PACK()                                                                               \
  do {                                                                                            \
    _Pragma("unroll") for (int r = 0; r < 16; r++) {                                              \
      s0[r] = __builtin_exp2f(s0[r]);                                                             \
      s1[r] = __builtin_exp2f(s1[r]);                                                             \
    }                                                                                             \
    int cw[8];                                                                                    \
    _Pragma("unroll") for (int m = 0; m < 8; m++) {                                               \
      __hip_bfloat162 h2 = __float22bfloat162_rn(make_float2(s0[2 * m], s0[2 * m + 1]));          \
      cw[m] = *(int*)&h2;                                                                         \
    }                                                                                             \
    asm("v_permlane32_swap_b32 %0, %1" : "+v"(cw[0]), "+v"(cw[2]));                               \
    asm("v_permlane32_swap_b32 %0, %1" : "+v"(cw[1]), "+v"(cw[3]));                               \
    asm("v_permlane32_swap_b32 %0, %1" : "+v"(cw[4]), "+v"(cw[6]));                               \
    asm("v_permlane32_swap_b32 %0, %1" : "+v"(cw[5]), "+v"(cw[7]));                               \
    { int4 w0 = make_int4(cw[0], cw[1], cw[2], cw[3]); pA0 = *(bf16x8*)&w0; }                     \
    { int4 w1 = make_int4(cw[4], cw[5], cw[6], cw[7]); pA1 = *(bf16x8*)&w1; }                     \
    _Pragma("unroll") for (int m = 0; m < 8; m++) {                                               \
      __hip_bfloat162 h2 = __float22bfloat162_rn(make_float2(s1[2 * m], s1[2 * m + 1]));          \
      cw[m] = *(int*)&h2;                                                                         \
    }                                                                                             \
    asm("v_permlane32_swap_b32 %0, %1" : "+v"(cw[0]), "+v"(cw[2]));                               \
    asm("v_permlane32_swap_b32 %0, %1" : "+v"(cw[1]), "+v"(cw[3]));                               \
    asm("v_permlane32_swap_b32 %0, %1" : "+v"(cw[4]), "+v"(cw[6]));                               \
    asm("v_permlane32_swap_b32 %0, %1" : "+v"(cw[5]), "+v"(cw[7]));                               \
    { int4 w0 = make_int4(cw[0], cw[1], cw[2], cw[3]); pB0 = *(bf16x8*)&w0; }                     \
    { int4 w1 = make_int4(cw[4], cw[5], cw[6], cw[7]); pB1 = *(bf16x8*)&w1; }                     \
  } while (0)

#define PV_TILE(buf)                                                                              \
  do {                                                                                            \
    const char* VtB_ = (const char*)Vs[buf];                                                      \
    __builtin_amdgcn_s_setprio(1);                                                                \
    _Pragma("unroll") for (int kb = 0; kb < 2; kb++) {                                            \
      bf16x8 p0 = kb ? pB0 : pA0;                                                                 \
      bf16x8 p1 = kb ? pB1 : pA1;                                                                 \
      bf16x8 va0 = *(const bf16x8*)(VtB_ + ((l31 * 128 + kb * 64 + half * 16) ^ swz));            \
      bf16x8 vb0 = *(const bf16x8*)(VtB_ + (((32 + l31) * 128 + kb * 64 + half * 16) ^ swz));     \
      bf16x8 va1 = *(const bf16x8*)(VtB_ + ((l31 * 128 + kb * 64 + 32 + half * 16) ^ swz));       \
      bf16x8 vb1 = *(const bf16x8*)(VtB_ + (((32 + l31) * 128 + kb * 64 + 32 + half * 16) ^ swz));\
      mfma32_bf16(o0, va0, p0);                                                                   \
      mfma32_bf16(o1, vb0, p0);                                                                   \
      l_acc = __builtin_amdgcn_mfma_f32_32x32x16_bf16(onesv, p0, l_acc, 0, 0, 0);                 \
      mfma32_bf16(o0, va1, p1);                                                                   \
      mfma32_bf16(o1, vb1, p1);                                                                   \
      l_acc = __builtin_amdgcn_mfma_f32_32x32x16_bf16(onesv, p1, l_acc, 0, 0, 0);                 \
    }                                                                                             \
    __builtin_amdgcn_s_setprio(0);                                                                \
  } while (0)

  // ---- prologue: tiles 0,1 staged; QK(0) ----
  STAGE(0, 0);
  STAGE(1, 1);
  asm volatile("s_waitcnt vmcnt(2)" ::: "memory");  // tile0 landed (tile1 in flight)
  __builtin_amdgcn_s_barrier();
  __builtin_amdgcn_sched_barrier(0);
  QK_TILE(0);

  int cA = 0, cB = 1, cC = 2;
  for (int t = 0; t < NT - 1; ++t) {
    if (t + 2 < NT) STAGE(t + 2, cC);
    SMAX_PACK();            // VALU phase (hides staging latency)
    PV_TILE(cA);            // MFMA (incl. l accumulation)
    if (t < NT - 2)
      asm volatile("s_waitcnt vmcnt(2)" ::: "memory");
    else
      asm volatile("s_waitcnt vmcnt(0)" ::: "memory");
    __builtin_amdgcn_s_barrier();
    __builtin_amdgcn_sched_barrier(0);
    QK_TILE(cB);
    int tmp = cA; cA = cB; cB = cC; cC = tmp;
  }
  SMAX_PACK();
  PV_TILE(cA);

#undef STAGE
#undef QK_TILE
#undef SMAX_PACK
#undef PV_TILE

  // ---- epilogue: l comes straight from l_acc (all regs equal l[qrow]) ----
  float inv = 1.0f / l_acc[0];
  const int b = bh >> 4, h = bh & 15;
  const int trow = q0 + wave * 32 + l31;
  __hip_bfloat16* orow = Ob + ((size_t)(b * 2048 + trow)) * 1024 + h * 64;
#pragma unroll
  for (int db = 0; db < 2; db++) {
#pragma unroll
    for (int rq = 0; rq < 4; rq++) {
      int d0 = db * 32 + rq * 8 + half * 4;
      s16x4 w;
#pragma unroll
      for (int e = 0; e < 4; e++) {
        float val = (db == 0 ? o0[rq * 4 + e] : o1[rq * 4 + e]) * inv;
        w[e] = (short)__bfloat16_as_short(__float2bfloat16(val));
      }
      *(s16x4*)(orow + d0) = w;
    }
  }
}

extern "C" void kernel_launch(void* const* d_in, const int* in_sizes, int n_in,
                              void* d_out, int out_size, void* d_ws, size_t ws_size,
                              hipStream_t stream) {
  const float* x = (const float*)d_in[0];
  const float* w_qkv = (const float*)d_in[1];
  const float* w_out = (const float*)d_in[2];
  const float* b_out = (const float*)d_in[3];
  float* out = (float*)d_out;

  size_t need = (size_t)37748736 * 2;
  if (ws_size < need) return;
  __hip_bfloat16* wsp = (__hip_bfloat16*)d_ws;
  __hip_bfloat16* x_bf = wsp;                          // 8192*1024 (reused as attn out)
  __hip_bfloat16* wqkv_t = x_bf + 8192 * 1024;         // 3072*1024
  __hip_bfloat16* wout_t = wqkv_t + 3072 * 1024;       // 1024*1024
  __hip_bfloat16* qb = wout_t + 1024 * 1024;           // [bh][t][64]
  __hip_bfloat16* kb = qb + 8388608;                   // [bh][t][64]
  __hip_bfloat16* vt = kb + 8388608;                   // [bh][d][2048]
  __hip_bfloat16* ab = x_bf;

  prep<<<6144, 256, 0, stream>>>(x, x_bf, w_qkv, wqkv_t, w_out, wout_t);
  gemm256_qk<<<dim3(8, 32), 512, 0, stream>>>(x_bf, wqkv_t, qb, kb);
  gemm_bf16<2><<<dim3(8, 64), 256, 0, stream>>>(x_bf, wqkv_t, 8192, 3072, 1024,
                                                vt, nullptr, nullptr);
  attn_fwd<<<512, 512, 0, stream>>>(qb, kb, vt, ab);
  gemm_bf16<1><<<dim3(8, 64), 256, 0, stream>>>(ab, wout_t, 8192, 1024, 1024,
                                                nullptr, out, b_out);
}

// Round 17
// 222.070 us; speedup vs baseline: 1.0267x; 1.0267x over previous
//
#include <hip/hip_runtime.h>
#include <hip/hip_bf16.h>
#include <stdint.h>

// B=4, T=2048, INPUT_DIM=1024, DIM=64, H=16
typedef __attribute__((ext_vector_type(8))) short bf16x8;
typedef __attribute__((ext_vector_type(4))) short s16x4;
typedef __attribute__((ext_vector_type(4))) float f32x4;
typedef __attribute__((ext_vector_type(16))) float f32x16;

__device__ __forceinline__ void mfma_bf16(f32x4& c, bf16x8 a, bf16x8 b) {
  asm("v_mfma_f32_16x16x32_bf16 %0, %1, %2, %0" : "+v"(c) : "v"(a), "v"(b));
}
__device__ __forceinline__ void mfma32_bf16(f32x16& c, bf16x8 a, bf16x8 b) {
  asm("v_mfma_f32_32x32x16_bf16 %0, %1, %2, %0" : "+v"(c) : "v"(a), "v"(b));
}

__device__ __forceinline__ void gload_lds16(const void* g, void* lds) {
  __builtin_amdgcn_global_load_lds(
      (const __attribute__((address_space(1))) void*)g,
      (__attribute__((address_space(3))) void*)lds, 16, 0, 0);
}

// ---------------- fused prep: x cvt (blocks 0..2047), w_qkv T (2048..5119),
// ---------------- w_out T (5120..6143). Branch is block-uniform. ----------------
__global__ __launch_bounds__(256) void prep(
    const float* __restrict__ x, __hip_bfloat16* __restrict__ x_bf,
    const float* __restrict__ w_qkv, __hip_bfloat16* __restrict__ wqkv_t,
    const float* __restrict__ w_out, __hip_bfloat16* __restrict__ wout_t) {
  __shared__ float tile[32][33];
  const int bid = blockIdx.x, tid = threadIdx.x;
  if (bid < 2048) {
    int i = bid * 256 + tid;  // grid-stride x4 over 2M float4s
#pragma unroll
    for (int it = 0; it < 4; ++it) {
      float4 v = reinterpret_cast<const float4*>(x)[i];
      __hip_bfloat162 a = __float22bfloat162_rn(make_float2(v.x, v.y));
      __hip_bfloat162 b = __float22bfloat162_rn(make_float2(v.z, v.w));
      reinterpret_cast<__hip_bfloat162*>(x_bf)[i * 2] = a;
      reinterpret_cast<__hip_bfloat162*>(x_bf)[i * 2 + 1] = b;
      i += 2048 * 256;
    }
  } else {
    const float* in;
    __hip_bfloat16* outp;
    int R, C, bx, by;
    if (bid < 5120) {  // w_qkv: [1024][3072] -> [3072][1024]
      int idx = bid - 2048;
      in = w_qkv; outp = wqkv_t; R = 1024; C = 3072;
      bx = idx % 96; by = idx / 96;
    } else {           // w_out: [1024][1024] -> [1024][1024]^T
      int idx = bid - 5120;
      in = w_out; outp = wout_t; R = 1024; C = 1024;
      bx = idx & 31; by = idx >> 5;
    }
    const int tx = tid & 31, ty = tid >> 5;
    const int c0 = bx * 32, r0 = by * 32;
#pragma unroll
    for (int k = 0; k < 4; k++)
      tile[ty + 8 * k][tx] = in[(size_t)(r0 + ty + 8 * k) * C + c0 + tx];
    __syncthreads();
#pragma unroll
    for (int k = 0; k < 4; k++)
      outp[(size_t)(c0 + ty + 8 * k) * R + r0 + tx] =
          __float2bfloat16(tile[tx][ty + 8 * k]);
  }
}

// ---------------- bf16 GEMM, m97 structure: 128x128 tile, BK=32 ----------------
// 512 blocks (2/CU) — grid fills the machine for the N=1024 GEMMs.
// MODE 1: f32 out + bias ; MODE 2: V-tiles -> C^T scatter into Vt [bh][d][t]
template <int MODE>
__global__ __launch_bounds__(256) void gemm_bf16(
    const __hip_bfloat16* __restrict__ A, const __hip_bfloat16* __restrict__ Bt,
    int M, int N, int K,
    __hip_bfloat16* __restrict__ vt,
    float* __restrict__ outp, const float* __restrict__ bias) {
  constexpr int BK = 32;
  __shared__ __align__(16) __hip_bfloat16 As[128 * BK];
  __shared__ __align__(16) __hip_bfloat16 Bs[128 * BK];
  const int tid = threadIdx.x;
  const int wave = tid >> 6, lane = tid & 63;
  const int wr = wave >> 1, wc = wave & 1;
  const int m0 = blockIdx.y * 128;
  const int n0 = (MODE == 2 ? 2048 : 0) + blockIdx.x * 128;

  f32x4 acc[4][4];
#pragma unroll
  for (int i = 0; i < 4; i++)
#pragma unroll
    for (int j = 0; j < 4; j++) acc[i][j] = (f32x4)(0.0f);

  const int c0 = wave * 2, c1 = c0 + 1;
  const int srow0 = c0 * 16 + (lane >> 2);
  const int srow1 = c1 * 16 + (lane >> 2);
  const int scol = (lane & 3) * 8;
  const __hip_bfloat16* Ag0 = A + (size_t)(m0 + srow0) * K + scol;
  const __hip_bfloat16* Ag1 = A + (size_t)(m0 + srow1) * K + scol;
  const __hip_bfloat16* Bg0 = Bt + (size_t)(n0 + srow0) * K + scol;
  const __hip_bfloat16* Bg1 = Bt + (size_t)(n0 + srow1) * K + scol;
  __hip_bfloat16* AsP0 = &As[c0 * 512];
  __hip_bfloat16* AsP1 = &As[c1 * 512];
  __hip_bfloat16* BsP0 = &Bs[c0 * 512];
  __hip_bfloat16* BsP1 = &Bs[c1 * 512];

  for (int kk = 0; kk < K; kk += BK) {
    gload_lds16(Ag0 + kk, AsP0);
    gload_lds16(Ag1 + kk, AsP1);
    gload_lds16(Bg0 + kk, BsP0);
    gload_lds16(Bg1 + kk, BsP1);
    __syncthreads();
    bf16x8 af[4], bfr[4];
#pragma unroll
    for (int i = 0; i < 4; i++)
      af[i] = *(const bf16x8*)&As[(wr * 64 + i * 16 + (lane & 15)) * BK + (lane >> 4) * 8];
#pragma unroll
    for (int j = 0; j < 4; j++)
      bfr[j] = *(const bf16x8*)&Bs[(wc * 64 + j * 16 + (lane & 15)) * BK + (lane >> 4) * 8];
#pragma unroll
    for (int i = 0; i < 4; i++)
#pragma unroll
      for (int j = 0; j < 4; j++) {
        if constexpr (MODE == 2)
          mfma_bf16(acc[i][j], bfr[j], af[i]);  // D = C^T fragment
        else
          mfma_bf16(acc[i][j], af[i], bfr[j]);
      }
    __syncthreads();
  }

  if constexpr (MODE == 2) {
#pragma unroll
    for (int j = 0; j < 4; j++) {
#pragma unroll
      for (int r = 0; r < 4; r++) {
        int nrow = n0 + wc * 64 + j * 16 + (lane >> 4) * 4 + r;  // 2048 + h*64 + d
        int h = (nrow >> 6) & 15;
        int d = nrow & 63;
#pragma unroll
        for (int i = 0; i < 4; i++) {
          int tcol = m0 + wr * 64 + i * 16 + (lane & 15);  // b*2048 + t
          int b = tcol >> 11, t = tcol & 2047;
          vt[(((size_t)b * 16 + h) * 64 + d) * 2048 + t] = __float2bfloat16(acc[i][j][r]);
        }
      }
    }
  } else {
#pragma unroll
    for (int j = 0; j < 4; j++) {
      int col = n0 + wc * 64 + j * 16 + (lane & 15);
      float bv = bias[col];
#pragma unroll
      for (int i = 0; i < 4; i++) {
#pragma unroll
        for (int r = 0; r < 4; r++) {
          int row = m0 + wr * 64 + i * 16 + (lane >> 4) * 4 + r;
          outp[(size_t)row * N + col] = acc[i][j][r] + bv;
        }
      }
    }
  }
}

// ---------------- 256x256 4-phase GEMM for Q/K (T2+T3+T5), 256 blocks ----------------
__global__ __launch_bounds__(512, 2) void gemm256_qk(
    const __hip_bfloat16* __restrict__ A, const __hip_bfloat16* __restrict__ Bt,
    __hip_bfloat16* __restrict__ qb, __hip_bfloat16* __restrict__ kb) {
  __shared__ __align__(16) __hip_bfloat16 lds[65536];  // 128KB
  char* ldsB = (char*)lds;
  const int tid = threadIdx.x, wave = tid >> 6, lane = tid & 63;
  const int wr = wave >> 2, wc = wave & 3;
  const int r15 = lane & 15, hi = lane >> 4;
  const int m0 = blockIdx.y * 256, n0 = blockIdx.x * 256;

  f32x4 acc[8][4];
#pragma unroll
  for (int i = 0; i < 8; i++)
#pragma unroll
    for (int j = 0; j < 4; j++) acc[i][j] = (f32x4)(0.0f);

  const int srow = lane >> 3;
  const int q8 = (lane & 7) ^ srow;  // pre-swizzled source chunk (rule #21)

  const int cs0 = ((hi) ^ (r15 & 7)) << 4;
  const int cs1 = ((4 + hi) ^ (r15 & 7)) << 4;

#define G256_STAGE_HALF(kt, tb, h)                                                     \
  do {                                                                                 \
    const __hip_bfloat16* gsrc_ = ((h) < 2)                                            \
        ? A + (size_t)(m0 + (h) * 128) * 1024 + (kt) * 64                              \
        : Bt + (size_t)(n0 + ((h) - 2) * 128) * 1024 + (kt) * 64;                      \
    char* dst_ = ldsB + (tb) * 65536 + (h) * 16384 + wave * 2048;                      \
    gload_lds16(gsrc_ + (size_t)(wave * 16 + srow) * 1024 + q8 * 8, dst_);             \
    gload_lds16(gsrc_ + (size_t)(wave * 16 + 8 + srow) * 1024 + q8 * 8, dst_ + 1024);  \
  } while (0)

#pragma unroll
  for (int h = 0; h < 4; h++) G256_STAGE_HALF(0, 0, h);
  asm volatile("s_waitcnt vmcnt(0)" ::: "memory");
  __builtin_amdgcn_s_barrier();

  bf16x8 af[4][2];
  for (int kt = 0; kt < 16; ++kt) {
    const int cur = kt & 1;
    const char* ab_ = ldsB + cur * 65536 + wr * 16384;
    const char* bb_ = ldsB + cur * 65536 + 32768 + (wc >> 1) * 16384;
#pragma unroll
    for (int p = 0; p < 4; p++) {
      const int qm = p >> 1, qn = p & 1;
      if (qn == 0) {
#pragma unroll
        for (int m = 0; m < 4; m++) {
          int hrow = (qm * 4 + m) * 16 + r15;
          af[m][0] = *(const bf16x8*)(ab_ + hrow * 128 + cs0);
          af[m][1] = *(const bf16x8*)(ab_ + hrow * 128 + cs1);
        }
      }
      bf16x8 bfv[2][2];
#pragma unroll
      for (int n = 0; n < 2; n++) {
        int hrow = (wc & 1) * 64 + (qn * 2 + n) * 16 + r15;
        bfv[n][0] = *(const bf16x8*)(bb_ + hrow * 128 + cs0);
        bfv[n][1] = *(const bf16x8*)(bb_ + hrow * 128 + cs1);
      }
      if (kt < 15) G256_STAGE_HALF(kt + 1, cur ^ 1, p);
      __builtin_amdgcn_s_barrier();
      asm volatile("s_waitcnt lgkmcnt(0)" ::: "memory");
      __builtin_amdgcn_sched_barrier(0);
      __builtin_amdgcn_s_setprio(1);
#pragma unroll
      for (int m = 0; m < 4; m++)
#pragma unroll
        for (int n = 0; n < 2; n++)
#pragma unroll
          for (int ks = 0; ks < 2; ks++)
            mfma_bf16(acc[qm * 4 + m][qn * 2 + n], af[m][ks], bfv[n][ks]);
      __builtin_amdgcn_s_setprio(0);
      if (p == 3) asm volatile("s_waitcnt vmcnt(0)" ::: "memory");
      __builtin_amdgcn_s_barrier();
    }
  }
#undef G256_STAGE_HALF

#pragma unroll
  for (int j = 0; j < 4; j++) {
    int col = n0 + wc * 64 + j * 16 + r15;
    int sel = col >> 10;  // 0=Q, 1=K
    int h = (col >> 6) & 15;
    int d = col & 63;
    __hip_bfloat16* dst = sel ? kb : qb;
    float scl = sel ? 1.0f : 0.18033688f;  // Q: 1/sqrt(64) * log2(e)
#pragma unroll
    for (int i = 0; i < 8; i++) {
#pragma unroll
      for (int r = 0; r < 4; r++) {
        int row = m0 + wr * 128 + i * 16 + hi * 4 + r;
        int b = row >> 11, t = row & 2047;
        dst[(((size_t)b * 16 + h) * 2048 + t) * 64 + d] = __float2bfloat16(acc[i][j][r] * scl);
      }
    }
  }
}

// ---------------- flash attention, 8 waves, 32x32 MFMA, NO-MAX softmax ----------------
// ROUND-15-EXACT (measured 222.35us total / attn 121.1us, VGPR 60, no spill).
// Runtime 3-buffer rotation; l-via-builtin-MFMA (l_acc = mfma32(ones, P-frag)).
// r16's persistent-zc delta regressed (spill) and is reverted.
__global__ __launch_bounds__(512, 4) void attn_fwd(
    const __hip_bfloat16* __restrict__ Qb, const __hip_bfloat16* __restrict__ Kb,
    const __hip_bfloat16* __restrict__ Vtg, __hip_bfloat16* __restrict__ Ob) {
  constexpr int T = 2048, NT = T / 64;
  __shared__ __align__(16) __hip_bfloat16 Ks[3][4096];  // [key][d] image, swizzled
  __shared__ __align__(16) __hip_bfloat16 Vs[3][4096];  // [d][key] image, swizzled
  const int tid = threadIdx.x, wave = tid >> 6, lane = tid & 63;

  // XCD-aware swizzle: 512 blocks = 8 XCD x 64; XCD x gets bh 8x..8x+7
  int id = ((int)blockIdx.x & 7) * 64 + ((int)blockIdx.x >> 3);
  const int bh = id >> 3, q0 = (id & 7) * 256;
  const size_t baseQ = (size_t)bh * T * 64;
  const size_t baseV = (size_t)bh * 64 * T;
  const int l31 = lane & 31, half = lane >> 5;

  // Q fragments (B-operand): lane holds Q[qrow=l31][k = 16ks + half*8 + j]
  bf16x8 qf[4];
  const int qrow = q0 + wave * 32 + l31;
#pragma unroll
  for (int ks = 0; ks < 4; ks++)
    qf[ks] = *(const bf16x8*)&Qb[baseQ + (size_t)qrow * 64 + ks * 16 + half * 8];

  f32x16 o0 = (f32x16)(0.0f), o1 = (f32x16)(0.0f);
  f32x16 l_acc = (f32x16)(0.0f);  // l via builtin MFMA (all regs = l[qrow])
  bf16x8 onesv;                   // bf16 1.0 splat (A-operand)
#pragma unroll
  for (int j = 0; j < 8; j++) onesv[j] = (short)0x3F80;
  f32x16 s0, s1;
  bf16x8 pA0, pA1, pB0, pB1;  // packed P fragments (keys 0-15,16-31,32-47,48-63)

  const int sr = lane >> 3;         // 0..7
  const int q8 = (lane & 7) ^ sr;   // pre-swizzled 16B-chunk within row
  const char* KgB = (const char*)(Kb + baseQ);
  const char* VgB = (const char*)(Vtg + baseV);
  const int swz = (l31 & 7) << 4;   // read-side XOR (row&7 = lane&7)

#define STAGE(kt, buf)                                                                            \
  do {                                                                                            \
    gload_lds16(KgB + (size_t)((kt) * 64 + wave * 8 + sr) * 128 + q8 * 16,                        \
                (char*)Ks[buf] + wave * 1024);                                                    \
    gload_lds16(VgB + (size_t)(wave * 8 + sr) * 4096 + (kt) * 128 + q8 * 16,                      \
                (char*)Vs[buf] + wave * 1024);                                                    \
  } while (0)

#define QK_TILE(buf)                                                                              \
  do {                                                                                            \
    const char* KsB_ = (const char*)Ks[buf];                                                      \
    _Pragma("unroll") for (int r = 0; r < 16; r++) { s0[r] = 0.0f; s1[r] = 0.0f; }                \
    __builtin_amdgcn_s_setprio(1);                                                                \
    _Pragma("unroll") for (int ks = 0; ks < 4; ks++) {                                            \
      bf16x8 kf0 = *(const bf16x8*)(KsB_ + ((l31 * 128 + ks * 32 + half * 16) ^ swz));            \
      bf16x8 kf1 = *(const bf16x8*)(KsB_ + (((32 + l31) * 128 + ks * 32 + half * 16) ^ swz));     \
      mfma32_bf16(s0, kf0, qf[ks]);                                                               \
      mfma32_bf16(s1, kf1, qf[ks]);                                                               \
    }                                                                                             \
    __builtin_amdgcn_s_setprio(0);                                                                \
  } while (0)

  // no-max softmax: P = 2^s; pack into pA/pB; s0/s1 die (l computed in PV via MFMA)
#define SMAX_PACK()                                                                               \
  do {                                                                                            \
    _Pragma("unroll") for (int r = 0; r < 16; r++) {                                              \
      s0[r] = __builtin_exp2f(s0[r]);                                                             \
      s1[r] = __builtin_exp2f(s1[r]);                                                             \
    }                                                                                             \
    int cw[8];                                                                                    \
    _Pragma("unroll") for (int m = 0; m < 8; m++) {                                               \
      __hip_bfloat162 h2 = __float22bfloat162_rn(make_float2(s0[2 * m], s0[2 * m + 1]));          \
      cw[m] = *(int*)&h2;                                                                         \
    }                                                                                             \
    asm("v_permlane32_swap_b32 %0, %1" : "+v"(cw[0]), "+v"(cw[2]));                               \
    asm("v_permlane32_swap_b32 %0, %1" : "+v"(cw[1]), "+v"(cw[3]));                               \
    asm("v_permlane32_swap_b32 %0, %1" : "+v"(cw[4]), "+v"(cw[6]));                               \
    asm("v_permlane32_swap_b32 %0, %1" : "+v"(cw[5]), "+v"(cw[7]));                               \
    { int4 w0 = make_int4(cw[0], cw[1], cw[2], cw[3]); pA0 = *(bf16x8*)&w0; }                     \
    { int4 w1 = make_int4(cw[4], cw[5], cw[6], cw[7]); pA1 = *(bf16x8*)&w1; }                     \
    _Pragma("unroll") for (int m = 0; m < 8; m++) {                                               \
      __hip_bfloat162 h2 = __float22bfloat162_rn(make_float2(s1[2 * m], s1[2 * m + 1]));          \
      cw[m] = *(int*)&h2;                                                                         \
    }                                                                                             \
    asm("v_permlane32_swap_b32 %0, %1" : "+v"(cw[0]), "+v"(cw[2]));                               \
    asm("v_permlane32_swap_b32 %0, %1" : "+v"(cw[1]), "+v"(cw[3]));                               \
    asm("v_permlane32_swap_b32 %0, %1" : "+v"(cw[4]), "+v"(cw[6]));                               \
    asm("v_permlane32_swap_b32 %0, %1" : "+v"(cw[5]), "+v"(cw[7]));                               \
    { int4 w0 = make_int4(cw[0], cw[1], cw[2], cw[3]); pB0 = *(bf16x8*)&w0; }                     \
    { int4 w1 = make_int4(cw[4], cw[5], cw[6], cw[7]); pB1 = *(bf16x8*)&w1; }                     \
  } while (0)

#define PV_TILE(buf)                                                                              \
  do {                                                                                            \
    const char* VtB_ = (const char*)Vs[buf];                                                      \
    __builtin_amdgcn_s_setprio(1);                                                                \
    _Pragma("unroll") for (int kb = 0; kb < 2; kb++) {                                            \
      bf16x8 p0 = kb ? pB0 : pA0;                                                                 \
      bf16x8 p1 = kb ? pB1 : pA1;                                                                 \
      bf16x8 va0 = *(const bf16x8*)(VtB_ + ((l31 * 128 + kb * 64 + half * 16) ^ swz));            \
      bf16x8 vb0 = *(const bf16x8*)(VtB_ + (((32 + l31) * 128 + kb * 64 + half * 16) ^ swz));     \
      bf16x8 va1 = *(const bf16x8*)(VtB_ + ((l31 * 128 + kb * 64 + 32 + half * 16) ^ swz));       \
      bf16x8 vb1 = *(const bf16x8*)(VtB_ + (((32 + l31) * 128 + kb * 64 + 32 + half * 16) ^ swz));\
      mfma32_bf16(o0, va0, p0);                                                                   \
      mfma32_bf16(o1, vb0, p0);                                                                   \
      l_acc = __builtin_amdgcn_mfma_f32_32x32x16_bf16(onesv, p0, l_acc, 0, 0, 0);                 \
      mfma32_bf16(o0, va1, p1);                                                                   \
      mfma32_bf16(o1, vb1, p1);                                                                   \
      l_acc = __builtin_amdgcn_mfma_f32_32x32x16_bf16(onesv, p1, l_acc, 0, 0, 0);                 \
    }                                                                                             \
    __builtin_amdgcn_s_setprio(0);                                                                \
  } while (0)

  // ---- prologue: tiles 0,1 staged; QK(0) ----
  STAGE(0, 0);
  STAGE(1, 1);
  asm volatile("s_waitcnt vmcnt(2)" ::: "memory");  // tile0 landed (tile1 in flight)
  __builtin_amdgcn_s_barrier();
  __builtin_amdgcn_sched_barrier(0);
  QK_TILE(0);

  int cA = 0, cB = 1, cC = 2;
  for (int t = 0; t < NT - 1; ++t) {
    if (t + 2 < NT) STAGE(t + 2, cC);
    SMAX_PACK();            // VALU phase (hides staging latency)
    PV_TILE(cA);            // MFMA (incl. l accumulation)
    if (t < NT - 2)
      asm volatile("s_waitcnt vmcnt(2)" ::: "memory");
    else
      asm volatile("s_waitcnt vmcnt(0)" ::: "memory");
    __builtin_amdgcn_s_barrier();
    __builtin_amdgcn_sched_barrier(0);
    QK_TILE(cB);
    int tmp = cA; cA = cB; cB = cC; cC = tmp;
  }
  SMAX_PACK();
  PV_TILE(cA);

#undef STAGE
#undef QK_TILE
#undef SMAX_PACK
#undef PV_TILE

  // ---- epilogue: l comes straight from l_acc (all regs equal l[qrow]) ----
  float inv = 1.0f / l_acc[0];
  const int b = bh >> 4, h = bh & 15;
  const int trow = q0 + wave * 32 + l31;
  __hip_bfloat16* orow = Ob + ((size_t)(b * 2048 + trow)) * 1024 + h * 64;
#pragma unroll
  for (int db = 0; db < 2; db++) {
#pragma unroll
    for (int rq = 0; rq < 4; rq++) {
      int d0 = db * 32 + rq * 8 + half * 4;
      s16x4 w;
#pragma unroll
      for (int e = 0; e < 4; e++) {
        float val = (db == 0 ? o0[rq * 4 + e] : o1[rq * 4 + e]) * inv;
        w[e] = (short)__bfloat16_as_short(__float2bfloat16(val));
      }
      *(s16x4*)(orow + d0) = w;
    }
  }
}

extern "C" void kernel_launch(void* const* d_in, const int* in_sizes, int n_in,
                              void* d_out, int out_size, void* d_ws, size_t ws_size,
                              hipStream_t stream) {
  const float* x = (const float*)d_in[0];
  const float* w_qkv = (const float*)d_in[1];
  const float* w_out = (const float*)d_in[2];
  const float* b_out = (const float*)d_in[3];
  float* out = (float*)d_out;

  size_t need = (size_t)37748736 * 2;
  if (ws_size < need) return;
  __hip_bfloat16* wsp = (__hip_bfloat16*)d_ws;
  __hip_bfloat16* x_bf = wsp;                          // 8192*1024 (reused as attn out)
  __hip_bfloat16* wqkv_t = x_bf + 8192 * 1024;         // 3072*1024
  __hip_bfloat16* wout_t = wqkv_t + 3072 * 1024;       // 1024*1024
  __hip_bfloat16* qb = wout_t + 1024 * 1024;           // [bh][t][64]
  __hip_bfloat16* kb = qb + 8388608;                   // [bh][t][64]
  __hip_bfloat16* vt = kb + 8388608;                   // [bh][d][2048]
  __hip_bfloat16* ab = x_bf;

  prep<<<6144, 256, 0, stream>>>(x, x_bf, w_qkv, wqkv_t, w_out, wout_t);
  gemm256_qk<<<dim3(8, 32), 512, 0, stream>>>(x_bf, wqkv_t, qb, kb);
  gemm_bf16<2><<<dim3(8, 64), 256, 0, stream>>>(x_bf, wqkv_t, 8192, 3072, 1024,
                                                vt, nullptr, nullptr);
  attn_fwd<<<512, 512, 0, stream>>>(qb, kb, vt, ab);
  gemm_bf16<1><<<dim3(8, 64), 256, 0, stream>>>(ab, wout_t, 8192, 1024, 1024,
                                                nullptr, out, b_out);
}